// Round 11
// baseline (114.012 us; speedup 1.0000x reference)
//
#include <hip/hip_runtime.h>
#include <hip/hip_bf16.h>

// Only the l=1 path reaches the output (g0/g2/c0/c2/w_tp0/w_tp2/L0/L2e are dead).
// t[i] = MLP(node i) @ (W_m2@w_tp1) + b_m2@w_tp1 ; enc = agg(segsum(t x sqrt3*pos)) @ (L1o@L_out)/64
// r9c: 32-node waves (2x TLP), v_cvt_pk_bf16_f32 packing, batched-rcp gelu, and the
// segment reduction FUSED into the node kernel via per-graph atomics (no T round-trip).

typedef __attribute__((ext_vector_type(8))) short bf16x8;
typedef __attribute__((ext_vector_type(4))) float f32x4;
typedef unsigned short ushort_t;

#define SBW 72   // LDS act-row stride in ushorts: 64 cols + 8 pad (144B rows, 16B-aligned)

__device__ __forceinline__ unsigned rnebits(float x) {   // RNE, bf16 in top 16 bits (prep only)
    unsigned u = __float_as_uint(x);
    return u + 0x7fffu + ((u >> 16) & 1u);
}
__device__ __forceinline__ ushort_t f2bf(float x) { return (ushort_t)(rnebits(x) >> 16); }
__device__ __forceinline__ float bf2f(ushort_t h) { return __uint_as_float(((unsigned)h) << 16); }
__device__ __forceinline__ unsigned pk2(float lo, float hi) {   // HW v_cvt_pk_bf16_f32 (RNE)
    __hip_bfloat162 h2 = __float22bfloat162_rn(make_float2(lo, hi));
    unsigned r;
    __builtin_memcpy(&r, &h2, 4);
    return r;
}
__device__ __forceinline__ void ds_order_fence() {   // compile-time: DS ops may not cross
    __builtin_amdgcn_sched_barrier(0x7F);
}

// batched gelu pair: gelu(x) = x - x*rcp(exp2(y)+1), y = x*(C + Ca*x^2) clamped to 60
// one v_rcp shared by two values: 1/sa = rcp(sa*sb)*sb
__device__ __forceinline__ void gelu2(float& a, float& b) {
    float ya = fminf(a * fmaf(0.10294324f, a * a, 2.3022082f), 60.0f);
    float yb = fminf(b * fmaf(0.10294324f, b * b, 2.3022082f), 60.0f);
    float sa = __builtin_amdgcn_exp2f(ya) + 1.0f;
    float sb = __builtin_amdgcn_exp2f(yb) + 1.0f;
    float R  = __builtin_amdgcn_rcpf(sa * sb);
    a = fmaf(-a, R * sb, a);
    b = fmaf(-b, R * sa, b);
}

// ---------------- prep ----------------
// wb ushort layout: layer L hi at L*8192, lo at L*8192+4096, all [64 feat][64 k] row-major.
//  L0=W_rbf0 zero-padded | L1=W_rbf1 | L2=W_m0[0:64] | L3=W_m1 | L4=Wc=W_m2@w_tp1
__global__ __launch_bounds__(256)
void prep_kernel(const float* __restrict__ W_rbf0, const float* __restrict__ W_rbf1,
                 const float* __restrict__ W_m0, const float* __restrict__ W_m1,
                 const float* __restrict__ W_m2, const float* __restrict__ b_m0,
                 const float* __restrict__ b_m2, const float* __restrict__ w_tp1,
                 const float* __restrict__ L1o, const float* __restrict__ L_out,
                 const float* __restrict__ node_table, const int* __restrict__ batch,
                 ushort_t* __restrict__ wb, float* __restrict__ tblc,
                 float* __restrict__ bc, float* __restrict__ Lcomb,
                 int* __restrict__ seg, int N, int G)
{
    if (blockIdx.x >= 127) {   // ---- seg part ----
        int i = (blockIdx.x - 127) * 256 + threadIdx.x;
        if (i >= N) return;
        int bi = batch[i];
        int bprev = (i == 0) ? -1 : batch[i - 1];
        for (int g = bprev + 1; g <= bi; ++g) seg[g] = i;
        if (i == N - 1) for (int g = bi + 1; g <= G; ++g) seg[g] = N;
        return;
    }
    int idx = blockIdx.x * 256 + threadIdx.x;   // fold part, 32384 items
    float w;
    ushort_t *dh, *dl;
    if (idx < 4096) {                    // L0: W_rbf0 zero-padded [f][64]
        int f = idx >> 6, k = idx & 63;
        w = (k < 32) ? W_rbf0[k * 64 + f] : 0.0f;
        dh = wb + idx; dl = wb + 4096 + idx;
    } else if (idx < 8192) {             // L1: W_rbf1 [f][64]
        int j = idx - 4096, f = j >> 6, k = j & 63;
        w = W_rbf1[k * 64 + f]; dh = wb + 8192 + j; dl = wb + 12288 + j;
    } else if (idx < 12288) {            // L2: W_m0 rows 0..63 [f][64]
        int j = idx - 8192, f = j >> 6, k = j & 63;
        w = W_m0[k * 64 + f]; dh = wb + 16384 + j; dl = wb + 20480 + j;
    } else if (idx < 16384) {            // L3: W_m1 [f][64]
        int j = idx - 12288, f = j >> 6, k = j & 63;
        w = W_m1[k * 64 + f]; dh = wb + 24576 + j; dl = wb + 28672 + j;
    } else if (idx < 20480) {            // L4: Wc[f][k] = sum_j W_m2[k][j]*w_tp1[j][f]
        int j = idx - 16384, f = j >> 6, k = j & 63;
        float s = 0.f;
        for (int jj = 0; jj < 64; ++jj) s = fmaf(W_m2[k * 64 + jj], w_tp1[jj * 64 + f], s);
        w = s; dh = wb + 32768 + j; dl = wb + 36864 + j;
    } else if (idx < 26880) {            // tblc[zz][f] = b_m0[f] + table[zz]@W_m0[64:96]  (f32)
        int j = idx - 20480, zz = j >> 6, f = j & 63;
        float s = b_m0[f];
        for (int k = 0; k < 32; ++k) s = fmaf(node_table[zz * 32 + k], W_m0[(64 + k) * 64 + f], s);
        tblc[j] = s;
        return;
    } else if (idx < 26944) {            // bc
        int b = idx - 26880;
        float s = 0.f;
        for (int k = 0; k < 64; ++k) s = fmaf(b_m2[k], w_tp1[k * 64 + b], s);
        bc[b] = s;
        return;
    } else if (idx < 32384) {            // Lcomb = (L1o@L_out)/64
        int j = idx - 26944, u = j / 85, v = j - 85 * u;
        float s = 0.f;
        for (int k = 0; k < 64; ++k) s = fmaf(L1o[u * 64 + k], L_out[k * 85 + v], s);
        Lcomb[j] = 0.015625f * s;
        return;
    } else return;
    ushort_t h = f2bf(w);
    *dh = h;
    *dl = f2bf(w - bf2f(h));
}

// ---------------- node MLP + fused segment reduction ----------------
// 4 waves/block; wave = 32 nodes; 5 uniform K=64 layers; then the wave reduces its
// own 32x64 t-tile against pos and atomically adds per-graph partials into g1[G][3][64].
__global__ __launch_bounds__(256, 4)
void node_mfma_kernel(const float* __restrict__ pos, const int* __restrict__ z,
                      const int* __restrict__ batch,
                      const ushort_t* __restrict__ wb, const float* __restrict__ tblc,
                      const float* __restrict__ b_rbf0, const float* __restrict__ b_rbf1,
                      const float* __restrict__ b_m1, const float* __restrict__ bc,
                      float* __restrict__ g1, int N, int ntiles)
{
    __shared__ ushort_t bufs[4 * 32 * SBW];   // 18432 B
    const int wid = threadIdx.x >> 6;
    const int lane = threadIdx.x & 63;
    const int tile = blockIdx.x * 4 + wid;
    if (tile >= ntiles) return;               // no block-wide syncs anywhere
    ushort_t* buf = bufs + wid * (32 * SBW);

    const int lrow = lane >> 4, lcol = lane & 15;
    const int nodebase = tile * 32;
    const int nend = (N - nodebase) < 32 ? (N - nodebase) : 32;

    // ---- stage rbf: lane handles node (lane&31), column half (lane>>5) ----
    float mypx, mypy, mypz;
    int myb;
    {
        const int nd = lane & 31, half = lane >> 5;
        int gn = nodebase + nd;
        if (gn > N - 1) gn = N - 1;
        mypx = pos[3 * gn]; mypy = pos[3 * gn + 1]; mypz = pos[3 * gn + 2];
        myb  = batch[gn];
        const float dist = sqrtf(mypx * mypx + mypy * mypy + mypz * mypz);
        unsigned rb[8];
        #pragma unroll
        for (int j = 0; j < 8; ++j) {
            float d0 = dist - (float)(half * 16 + 2 * j)     * (1.0f / 31.0f);
            float d1 = dist - (float)(half * 16 + 2 * j + 1) * (1.0f / 31.0f);
            rb[j] = pk2(__builtin_amdgcn_exp2f(-693.2149671554846f * d0 * d0),
                        __builtin_amdgcn_exp2f(-693.2149671554846f * d1 * d1));
        }
        uint4* dst = (uint4*)&buf[nd * SBW + half * 16];
        dst[0] = make_uint4(rb[0], rb[1], rb[2], rb[3]);
        dst[1] = make_uint4(rb[4], rb[5], rb[6], rb[7]);
        uint4* dz = (uint4*)&buf[nd * SBW + 32 + half * 16];   // zero cols 32..63
        dz[0] = make_uint4(0, 0, 0, 0);
        dz[1] = make_uint4(0, 0, 0, 0);
    }
    // z gather for layer-2 acc-init (node = n*16+lcol)
    int zn0, zn1;
    {
        int n0 = nodebase + 0  + lcol; if (n0 > N - 1) n0 = N - 1;
        int n1 = nodebase + 16 + lcol; if (n1 > N - 1) n1 = N - 1;
        zn0 = z[n0]; zn1 = z[n1];
    }
    ds_order_fence();

    #pragma unroll 1
    for (int L = 0; L < 5; ++L) {
        const ushort_t* whb = wb + L * 8192;
        f32x4 acc[4][2];
        if (L == 2) {   // per-node acc-init from tblc (f32-exact table contribution)
            const int zn[2] = {zn0, zn1};
            #pragma unroll
            for (int n = 0; n < 2; ++n) {
                const float* tp = tblc + zn[n] * 64 + lrow * 4;
                #pragma unroll
                for (int m = 0; m < 4; ++m) {
                    float4 bv = *(const float4*)(tp + m * 16);
                    acc[m][n][0] = bv.x; acc[m][n][1] = bv.y;
                    acc[m][n][2] = bv.z; acc[m][n][3] = bv.w;
                }
            }
        } else {
            const float* bp = (L == 0) ? b_rbf0 : (L == 1) ? b_rbf1 : (L == 3) ? b_m1 : bc;
            #pragma unroll
            for (int m = 0; m < 4; ++m) {
                float4 bv = *(const float4*)(bp + m * 16 + lrow * 4);
                #pragma unroll
                for (int n = 0; n < 2; ++n) {
                    acc[m][n][0] = bv.x; acc[m][n][1] = bv.y;
                    acc[m][n][2] = bv.z; acc[m][n][3] = bv.w;
                }
            }
        }
        #pragma unroll
        for (int kt = 0; kt < 2; ++kt) {
            const int kof = kt * 32 + lrow * 8;
            bf16x8 bb[2], ah[4], al[4];
            #pragma unroll
            for (int n = 0; n < 2; ++n)
                bb[n] = *(const bf16x8*)&buf[(n * 16 + lcol) * SBW + kof];
            #pragma unroll
            for (int m = 0; m < 4; ++m) {
                ah[m] = *(const bf16x8*)(whb + (m * 16 + lcol) * 64 + kof);
                al[m] = *(const bf16x8*)(whb + 4096 + (m * 16 + lcol) * 64 + kof);
            }
            #pragma unroll
            for (int m = 0; m < 4; ++m)
                #pragma unroll
                for (int n = 0; n < 2; ++n)
                    acc[m][n] = __builtin_amdgcn_mfma_f32_16x16x32_bf16(ah[m], bb[n], acc[m][n], 0, 0, 0);
            #pragma unroll
            for (int m = 0; m < 4; ++m)
                #pragma unroll
                for (int n = 0; n < 2; ++n)
                    acc[m][n] = __builtin_amdgcn_mfma_f32_16x16x32_bf16(al[m], bb[n], acc[m][n], 0, 0, 0);
        }
        ds_order_fence();   // all reads of buf done before in-place writes
        const bool act = (L == 0) | (L == 2) | (L == 3);
        #pragma unroll
        for (int m = 0; m < 4; ++m) {
            const int f0 = m * 16 + lrow * 4;
            #pragma unroll
            for (int n = 0; n < 2; ++n) {
                f32x4 v = acc[m][n];
                float v0 = v[0], v1 = v[1], v2 = v[2], v3 = v[3];
                if (act) { gelu2(v0, v1); gelu2(v2, v3); }
                uint2 pk;
                pk.x = pk2(v0, v1);
                pk.y = pk2(v2, v3);
                *(uint2*)&buf[(n * 16 + lcol) * SBW + f0] = pk;
            }
        }
        ds_order_fence();   // writes done before next layer's reads
    }

    // ---- fused segment reduction: lane = feature, iterate this wave's nodes ----
    {
        float a0 = 0.f, a1 = 0.f, a2 = 0.f;
        int curg = __shfl(myb, 0);
        for (int nd = 0; nd < nend; ++nd) {
            int bg = __shfl(myb, nd);            // wave-uniform graph id
            if (bg != curg) {
                atomicAdd(&g1[curg * 192 + lane],       a0);
                atomicAdd(&g1[curg * 192 + 64 + lane],  a1);
                atomicAdd(&g1[curg * 192 + 128 + lane], a2);
                a0 = a1 = a2 = 0.f;
                curg = bg;
            }
            float t = bf2f(buf[nd * SBW + lane]);
            float qx = __shfl(mypx, nd), qy = __shfl(mypy, nd), qz = __shfl(mypz, nd);
            a0 = fmaf(t, qx, a0);
            a1 = fmaf(t, qy, a1);
            a2 = fmaf(t, qz, a2);
        }
        atomicAdd(&g1[curg * 192 + lane],       a0);
        atomicAdd(&g1[curg * 192 + 64 + lane],  a1);
        atomicAdd(&g1[curg * 192 + 128 + lane], a2);
    }
}

// ---------------- final: scale + Lcomb matmul ----------------
__global__ __launch_bounds__(256)
void graph_final(const float* __restrict__ g1, const int* __restrict__ seg,
                 const float* __restrict__ Lcomb, float* __restrict__ out, int G) {
    __shared__ float g1s[4][64][3];
    const int lane = threadIdx.x & 63;
    const int wid = threadIdx.x >> 6;
    const int g = blockIdx.x * 4 + wid;
    const bool active = g < G;

    if (active) {
        int c = seg[g + 1] - seg[g];
        float cnt = (float)(c > 0 ? c : 1);
        float sc = 1.7320508075688772f * 0.125f * (1.0f + 1.0f / cnt);
        g1s[wid][lane][0] = g1[g * 192 + lane] * sc;
        g1s[wid][lane][1] = g1[g * 192 + 64 + lane] * sc;
        g1s[wid][lane][2] = g1[g * 192 + 128 + lane] * sc;
    }
    __syncthreads();
    if (!active) return;

    float o0 = 0.f, o1 = 0.f, o2 = 0.f, p0 = 0.f, p1 = 0.f, p2 = 0.f;
    const int v2 = 64 + lane;
    for (int u = 0; u < 64; ++u) {
        float b0 = g1s[wid][u][0], b1 = g1s[wid][u][1], b2 = g1s[wid][u][2];
        float l0 = Lcomb[u * 85 + lane];
        o0 = fmaf(b0, l0, o0); o1 = fmaf(b1, l0, o1); o2 = fmaf(b2, l0, o2);
        if (lane < 21) {
            float l1 = Lcomb[u * 85 + v2];
            p0 = fmaf(b0, l1, p0); p1 = fmaf(b1, l1, p1); p2 = fmaf(b2, l1, p2);
        }
    }
    float* og = out + (size_t)g * 255;
    og[3 * lane + 0] = o0; og[3 * lane + 1] = o1; og[3 * lane + 2] = o2;
    if (lane < 21) {
        og[3 * v2 + 0] = p0; og[3 * v2 + 1] = p1; og[3 * v2 + 2] = p2;
    }
}

extern "C" void kernel_launch(void* const* d_in, const int* in_sizes, int n_in,
                              void* d_out, int out_size, void* d_ws, size_t ws_size,
                              hipStream_t stream) {
    const float* pos        = (const float*)d_in[0];
    const int*   z          = (const int*)d_in[1];
    const int*   batch      = (const int*)d_in[2];
    const float* node_table = (const float*)d_in[3];
    const float* W_rbf0     = (const float*)d_in[4];
    const float* b_rbf0     = (const float*)d_in[5];
    const float* W_rbf1     = (const float*)d_in[6];
    const float* b_rbf1     = (const float*)d_in[7];
    const float* W_m0       = (const float*)d_in[8];
    const float* b_m0       = (const float*)d_in[9];
    const float* W_m1       = (const float*)d_in[10];
    const float* b_m1       = (const float*)d_in[11];
    const float* W_m2       = (const float*)d_in[12];
    const float* b_m2       = (const float*)d_in[13];
    const float* w_tp1      = (const float*)d_in[15];
    const float* L1o        = (const float*)d_in[18];
    const float* L_out      = (const float*)d_in[20];
    float* out = (float*)d_out;

    const int N = in_sizes[0] / 3;       // 200000
    const int G = out_size / 255;        // 8192
    const int ntiles = (N + 31) / 32;    // 6250

    char* ws = (char*)d_ws;
    float*    bc    = (float*)(ws + 0);           // 256 B
    float*    Lcomb = (float*)(ws + 256);         // 21760 -> 22016, pad 22528
    int*      seg   = (int*)(ws + 22528);         // 32772 -> 55300, pad 55552
    ushort_t* wb    = (ushort_t*)(ws + 55552);    // 81920 B -> 137472
    float*    tblc  = (float*)(ws + 137472);      // 25600 -> 163072
    float*    g1    = (float*)(ws + 163072);      // G*192*4 = 6291456 B

    (void)hipMemsetAsync(g1, 0, (size_t)G * 192 * sizeof(float), stream);

    const int segBlocks = (N + 255) / 256;
    prep_kernel<<<127 + segBlocks, 256, 0, stream>>>(
        W_rbf0, W_rbf1, W_m0, W_m1, W_m2, b_m0, b_m2, w_tp1, L1o, L_out,
        node_table, batch, wb, tblc, bc, Lcomb, seg, N, G);

    node_mfma_kernel<<<(ntiles + 3) / 4, 256, 0, stream>>>(
        pos, z, batch, wb, tblc, b_rbf0, b_rbf1, b_m1, bc, g1, N, ntiles);

    graph_final<<<(G + 3) / 4, 256, 0, stream>>>(g1, seg, Lcomb, out, G);
}

// Round 12
// 96.871 us; speedup vs baseline: 1.1769x; 1.1769x over previous
//
#include <hip/hip_runtime.h>
#include <hip/hip_bf16.h>

// Only the l=1 path reaches the output (g0/g2/c0/c2/w_tp0/w_tp2/L0/L2e are dead).
// t[i] = MLP(node i) @ (W_m2@w_tp1) + b_m2@w_tp1 ; enc = agg(segsum(t x sqrt3*pos)) @ (L1o@L_out)/64
// r12: activations stay IN REGISTERS between layers (shfl-based C->B fragment
// transpose); no LDS act buffer, no sched_barrier fences; LDS used once for the
// fused segment reduction. 64-node waves, weights streamed hi/lo bf16 from L2.

typedef __attribute__((ext_vector_type(8))) short bf16x8;
typedef __attribute__((ext_vector_type(4))) float f32x4;
typedef unsigned short ushort_t;

#define SBW 72   // LDS t-tile row stride in ushorts: 64 cols + 8 pad

__device__ __forceinline__ unsigned rnebits(float x) {   // RNE, bf16 in top 16 bits (prep only)
    unsigned u = __float_as_uint(x);
    return u + 0x7fffu + ((u >> 16) & 1u);
}
__device__ __forceinline__ ushort_t f2bf(float x) { return (ushort_t)(rnebits(x) >> 16); }
__device__ __forceinline__ float bf2f(ushort_t h) { return __uint_as_float(((unsigned)h) << 16); }
__device__ __forceinline__ unsigned pk2(float lo, float hi) {   // HW v_cvt_pk_bf16_f32 (RNE)
    __hip_bfloat162 h2 = __float22bfloat162_rn(make_float2(lo, hi));
    unsigned r;
    __builtin_memcpy(&r, &h2, 4);
    return r;
}

// batched gelu pair: gelu(x) = x - x*rcp(exp2(y)+1), y = x*(C + Ca*x^2) clamped to 60
__device__ __forceinline__ void gelu2(float& a, float& b) {
    float ya = fminf(a * fmaf(0.10294324f, a * a, 2.3022082f), 60.0f);
    float yb = fminf(b * fmaf(0.10294324f, b * b, 2.3022082f), 60.0f);
    float sa = __builtin_amdgcn_exp2f(ya) + 1.0f;
    float sb = __builtin_amdgcn_exp2f(yb) + 1.0f;
    float R  = __builtin_amdgcn_rcpf(sa * sb);
    a = fmaf(-a, R * sb, a);
    b = fmaf(-b, R * sa, b);
}

// ---------------- prep (unchanged from r11, passed) ----------------
// wb ushort layout: layer L hi at L*8192, lo at L*8192+4096, all [64 feat][64 k] row-major.
//  L0=W_rbf0 zero-padded | L1=W_rbf1 | L2=W_m0[0:64] | L3=W_m1 | L4=Wc=W_m2@w_tp1
__global__ __launch_bounds__(256)
void prep_kernel(const float* __restrict__ W_rbf0, const float* __restrict__ W_rbf1,
                 const float* __restrict__ W_m0, const float* __restrict__ W_m1,
                 const float* __restrict__ W_m2, const float* __restrict__ b_m0,
                 const float* __restrict__ b_m2, const float* __restrict__ w_tp1,
                 const float* __restrict__ L1o, const float* __restrict__ L_out,
                 const float* __restrict__ node_table, const int* __restrict__ batch,
                 ushort_t* __restrict__ wb, float* __restrict__ tblc,
                 float* __restrict__ bc, float* __restrict__ Lcomb,
                 int* __restrict__ seg, int N, int G)
{
    if (blockIdx.x >= 127) {   // ---- seg part ----
        int i = (blockIdx.x - 127) * 256 + threadIdx.x;
        if (i >= N) return;
        int bi = batch[i];
        int bprev = (i == 0) ? -1 : batch[i - 1];
        for (int g = bprev + 1; g <= bi; ++g) seg[g] = i;
        if (i == N - 1) for (int g = bi + 1; g <= G; ++g) seg[g] = N;
        return;
    }
    int idx = blockIdx.x * 256 + threadIdx.x;   // fold part, 32384 items
    float w;
    ushort_t *dh, *dl;
    if (idx < 4096) {                    // L0: W_rbf0 zero-padded [f][64]
        int f = idx >> 6, k = idx & 63;
        w = (k < 32) ? W_rbf0[k * 64 + f] : 0.0f;
        dh = wb + idx; dl = wb + 4096 + idx;
    } else if (idx < 8192) {             // L1: W_rbf1 [f][64]
        int j = idx - 4096, f = j >> 6, k = j & 63;
        w = W_rbf1[k * 64 + f]; dh = wb + 8192 + j; dl = wb + 12288 + j;
    } else if (idx < 12288) {            // L2: W_m0 rows 0..63 [f][64]
        int j = idx - 8192, f = j >> 6, k = j & 63;
        w = W_m0[k * 64 + f]; dh = wb + 16384 + j; dl = wb + 20480 + j;
    } else if (idx < 16384) {            // L3: W_m1 [f][64]
        int j = idx - 12288, f = j >> 6, k = j & 63;
        w = W_m1[k * 64 + f]; dh = wb + 24576 + j; dl = wb + 28672 + j;
    } else if (idx < 20480) {            // L4: Wc[f][k] = sum_j W_m2[k][j]*w_tp1[j][f]
        int j = idx - 16384, f = j >> 6, k = j & 63;
        float s = 0.f;
        for (int jj = 0; jj < 64; ++jj) s = fmaf(W_m2[k * 64 + jj], w_tp1[jj * 64 + f], s);
        w = s; dh = wb + 32768 + j; dl = wb + 36864 + j;
    } else if (idx < 26880) {            // tblc[zz][f] = b_m0[f] + table[zz]@W_m0[64:96]  (f32)
        int j = idx - 20480, zz = j >> 6, f = j & 63;
        float s = b_m0[f];
        for (int k = 0; k < 32; ++k) s = fmaf(node_table[zz * 32 + k], W_m0[(64 + k) * 64 + f], s);
        tblc[j] = s;
        return;
    } else if (idx < 26944) {            // bc
        int b = idx - 26880;
        float s = 0.f;
        for (int k = 0; k < 64; ++k) s = fmaf(b_m2[k], w_tp1[k * 64 + b], s);
        bc[b] = s;
        return;
    } else if (idx < 32384) {            // Lcomb = (L1o@L_out)/64
        int j = idx - 26944, u = j / 85, v = j - 85 * u;
        float s = 0.f;
        for (int k = 0; k < 64; ++k) s = fmaf(L1o[u * 64 + k], L_out[k * 85 + v], s);
        Lcomb[j] = 0.015625f * s;
        return;
    } else return;
    ushort_t h = f2bf(w);
    *dh = h;
    *dl = f2bf(w - bf2f(h));
}

// ---------------- node MLP, register-resident activations ----------------
// 4 waves/block; wave = 64 nodes; pk01/pk23[m][n] hold the current activation tile
// as packed bf16 in MFMA-C layout; per layer a shfl-transpose builds the B frags.
__global__ __launch_bounds__(256, 2)
void node_mfma_kernel(const float* __restrict__ pos, const int* __restrict__ z,
                      const int* __restrict__ batch,
                      const ushort_t* __restrict__ wb, const float* __restrict__ tblc,
                      const float* __restrict__ b_rbf0, const float* __restrict__ b_rbf1,
                      const float* __restrict__ b_m1, const float* __restrict__ bc,
                      float* __restrict__ g1, int N, int ntiles)
{
    __shared__ ushort_t bufs[4 * 64 * SBW];   // 36864 B: one 64x64 t-tile per wave
    const int wid = threadIdx.x >> 6;
    const int lane = threadIdx.x & 63;
    const int tile = blockIdx.x * 4 + wid;
    if (tile >= ntiles) return;               // no block-wide syncs anywhere
    ushort_t* buf = bufs + wid * (64 * SBW);

    const int lrow = lane >> 4, lcol = lane & 15;
    const int nodebase = tile * 64;
    const int nend = (N - nodebase) < 64 ? (N - nodebase) : 64;

    int gn = nodebase + lane;
    if (gn > N - 1) gn = N - 1;
    const float mypx = pos[3 * gn], mypy = pos[3 * gn + 1], mypz = pos[3 * gn + 2];
    const int   myb  = batch[gn];
    const float dist = sqrtf(mypx * mypx + mypy * mypy + mypz * mypz);

    // ---- activation state: packed bf16 pairs in MFMA-C layout ----
    // pk01[m][n] = feats (m*16+lrow*4 +0,+1), pk23 = (+2,+3), node n*16+lcol
    unsigned pk01[4][4], pk23[4][4];

    // ---- L0 input: rbf in pk layout (feat==k; real k<32 -> m=0,1; m=2,3 zero) ----
    #pragma unroll
    for (int n = 0; n < 4; ++n) {
        float d = __shfl(dist, n * 16 + lcol);
        #pragma unroll
        for (int m = 0; m < 2; ++m) {
            const int k0 = m * 16 + lrow * 4;
            float g0, g1v, g2, g3;
            {
                float d0 = d - (float)(k0 + 0) * (1.0f / 31.0f);
                float d1 = d - (float)(k0 + 1) * (1.0f / 31.0f);
                float d2 = d - (float)(k0 + 2) * (1.0f / 31.0f);
                float d3 = d - (float)(k0 + 3) * (1.0f / 31.0f);
                g0 = __builtin_amdgcn_exp2f(-693.2149671554846f * d0 * d0);
                g1v = __builtin_amdgcn_exp2f(-693.2149671554846f * d1 * d1);
                g2 = __builtin_amdgcn_exp2f(-693.2149671554846f * d2 * d2);
                g3 = __builtin_amdgcn_exp2f(-693.2149671554846f * d3 * d3);
            }
            pk01[m][n] = pk2(g0, g1v);
            pk23[m][n] = pk2(g2, g3);
        }
        pk01[2][n] = 0u; pk23[2][n] = 0u;
        pk01[3][n] = 0u; pk23[3][n] = 0u;
    }
    // z gather for layer-2 acc-init (node = n*16+lcol)
    int zn[4];
    #pragma unroll
    for (int n = 0; n < 4; ++n) {
        int nn = nodebase + n * 16 + lcol;
        if (nn > N - 1) nn = N - 1;
        zn[n] = z[nn];
    }

    const int laneA = (lrow & 1) * 32 + lcol;   // source lanes for the shfl-transpose
    const bool hiSel = (lrow & 2) != 0;

    #pragma unroll 1
    for (int L = 0; L < 5; ++L) {
        const ushort_t* whb = wb + L * 8192;

        // ---- shfl-transpose: pk (C layout) -> bb[n][kt] (B layout) ----
        bf16x8 bb[4][2];
        #pragma unroll
        for (int n = 0; n < 4; ++n)
            #pragma unroll
            for (int kt = 0; kt < 2; ++kt) {
                unsigned a0 = __shfl(pk01[2 * kt][n],     laneA);
                unsigned b0 = __shfl(pk01[2 * kt + 1][n], laneA);
                unsigned a1 = __shfl(pk23[2 * kt][n],     laneA);
                unsigned b1 = __shfl(pk23[2 * kt + 1][n], laneA);
                unsigned a2 = __shfl(pk01[2 * kt][n],     laneA + 16);
                unsigned b2 = __shfl(pk01[2 * kt + 1][n], laneA + 16);
                unsigned a3 = __shfl(pk23[2 * kt][n],     laneA + 16);
                unsigned b3 = __shfl(pk23[2 * kt + 1][n], laneA + 16);
                uint4 uu;
                uu.x = hiSel ? b0 : a0;
                uu.y = hiSel ? b1 : a1;
                uu.z = hiSel ? b2 : a2;
                uu.w = hiSel ? b3 : a3;
                __builtin_memcpy(&bb[n][kt], &uu, 16);
            }

        // ---- acc init ----
        f32x4 acc[4][4];
        if (L == 2) {   // per-node init from tblc (f32-exact table contribution)
            #pragma unroll
            for (int n = 0; n < 4; ++n) {
                const float* tp = tblc + zn[n] * 64 + lrow * 4;
                #pragma unroll
                for (int m = 0; m < 4; ++m) {
                    float4 bv = *(const float4*)(tp + m * 16);
                    acc[m][n][0] = bv.x; acc[m][n][1] = bv.y;
                    acc[m][n][2] = bv.z; acc[m][n][3] = bv.w;
                }
            }
        } else {
            const float* bp = (L == 0) ? b_rbf0 : (L == 1) ? b_rbf1 : (L == 3) ? b_m1 : bc;
            #pragma unroll
            for (int m = 0; m < 4; ++m) {
                float4 bv = *(const float4*)(bp + m * 16 + lrow * 4);
                #pragma unroll
                for (int n = 0; n < 4; ++n) {
                    acc[m][n][0] = bv.x; acc[m][n][1] = bv.y;
                    acc[m][n][2] = bv.z; acc[m][n][3] = bv.w;
                }
            }
        }

        // ---- MFMA: stream weights hi/lo from L2 ----
        #pragma unroll
        for (int kt = 0; kt < 2; ++kt) {
            const int kof = kt * 32 + lrow * 8;
            bf16x8 ah[4], al[4];
            #pragma unroll
            for (int m = 0; m < 4; ++m) {
                ah[m] = *(const bf16x8*)(whb + (m * 16 + lcol) * 64 + kof);
                al[m] = *(const bf16x8*)(whb + 4096 + (m * 16 + lcol) * 64 + kof);
            }
            #pragma unroll
            for (int m = 0; m < 4; ++m)
                #pragma unroll
                for (int n = 0; n < 4; ++n)
                    acc[m][n] = __builtin_amdgcn_mfma_f32_16x16x32_bf16(ah[m], bb[n][kt], acc[m][n], 0, 0, 0);
            #pragma unroll
            for (int m = 0; m < 4; ++m)
                #pragma unroll
                for (int n = 0; n < 4; ++n)
                    acc[m][n] = __builtin_amdgcn_mfma_f32_16x16x32_bf16(al[m], bb[n][kt], acc[m][n], 0, 0, 0);
        }

        // ---- epilogue: gelu + pack back into pk registers (no LDS) ----
        const bool act = (L == 0) | (L == 2) | (L == 3);
        #pragma unroll
        for (int m = 0; m < 4; ++m)
            #pragma unroll
            for (int n = 0; n < 4; ++n) {
                f32x4 v = acc[m][n];
                float v0 = v[0], v1 = v[1], v2 = v[2], v3 = v[3];
                if (act) { gelu2(v0, v1); gelu2(v2, v3); }
                pk01[m][n] = pk2(v0, v1);
                pk23[m][n] = pk2(v2, v3);
            }
    }

    // ---- write t tile to LDS once, then fused segment reduction ----
    #pragma unroll
    for (int m = 0; m < 4; ++m)
        #pragma unroll
        for (int n = 0; n < 4; ++n) {
            uint2 pk;
            pk.x = pk01[m][n];
            pk.y = pk23[m][n];
            *(uint2*)&buf[(n * 16 + lcol) * SBW + m * 16 + lrow * 4] = pk;
        }

    {
        float a0 = 0.f, a1 = 0.f, a2 = 0.f;
        int curg = __shfl(myb, 0);
        for (int nd = 0; nd < nend; ++nd) {
            int bg = __shfl(myb, nd);            // wave-uniform graph id
            if (bg != curg) {
                atomicAdd(&g1[curg * 192 + lane],       a0);
                atomicAdd(&g1[curg * 192 + 64 + lane],  a1);
                atomicAdd(&g1[curg * 192 + 128 + lane], a2);
                a0 = a1 = a2 = 0.f;
                curg = bg;
            }
            float t = bf2f(buf[nd * SBW + lane]);
            float qx = __shfl(mypx, nd), qy = __shfl(mypy, nd), qz = __shfl(mypz, nd);
            a0 = fmaf(t, qx, a0);
            a1 = fmaf(t, qy, a1);
            a2 = fmaf(t, qz, a2);
        }
        atomicAdd(&g1[curg * 192 + lane],       a0);
        atomicAdd(&g1[curg * 192 + 64 + lane],  a1);
        atomicAdd(&g1[curg * 192 + 128 + lane], a2);
    }
}

// ---------------- final: scale + Lcomb matmul (unchanged, passed) ----------------
__global__ __launch_bounds__(256)
void graph_final(const float* __restrict__ g1, const int* __restrict__ seg,
                 const float* __restrict__ Lcomb, float* __restrict__ out, int G) {
    __shared__ float g1s[4][64][3];
    const int lane = threadIdx.x & 63;
    const int wid = threadIdx.x >> 6;
    const int g = blockIdx.x * 4 + wid;
    const bool active = g < G;

    if (active) {
        int c = seg[g + 1] - seg[g];
        float cnt = (float)(c > 0 ? c : 1);
        float sc = 1.7320508075688772f * 0.125f * (1.0f + 1.0f / cnt);
        g1s[wid][lane][0] = g1[g * 192 + lane] * sc;
        g1s[wid][lane][1] = g1[g * 192 + 64 + lane] * sc;
        g1s[wid][lane][2] = g1[g * 192 + 128 + lane] * sc;
    }
    __syncthreads();
    if (!active) return;

    float o0 = 0.f, o1 = 0.f, o2 = 0.f, p0 = 0.f, p1 = 0.f, p2 = 0.f;
    const int v2 = 64 + lane;
    for (int u = 0; u < 64; ++u) {
        float b0 = g1s[wid][u][0], b1 = g1s[wid][u][1], b2 = g1s[wid][u][2];
        float l0 = Lcomb[u * 85 + lane];
        o0 = fmaf(b0, l0, o0); o1 = fmaf(b1, l0, o1); o2 = fmaf(b2, l0, o2);
        if (lane < 21) {
            float l1 = Lcomb[u * 85 + v2];
            p0 = fmaf(b0, l1, p0); p1 = fmaf(b1, l1, p1); p2 = fmaf(b2, l1, p2);
        }
    }
    float* og = out + (size_t)g * 255;
    og[3 * lane + 0] = o0; og[3 * lane + 1] = o1; og[3 * lane + 2] = o2;
    if (lane < 21) {
        og[3 * v2 + 0] = p0; og[3 * v2 + 1] = p1; og[3 * v2 + 2] = p2;
    }
}

extern "C" void kernel_launch(void* const* d_in, const int* in_sizes, int n_in,
                              void* d_out, int out_size, void* d_ws, size_t ws_size,
                              hipStream_t stream) {
    const float* pos        = (const float*)d_in[0];
    const int*   z          = (const int*)d_in[1];
    const int*   batch      = (const int*)d_in[2];
    const float* node_table = (const float*)d_in[3];
    const float* W_rbf0     = (const float*)d_in[4];
    const float* b_rbf0     = (const float*)d_in[5];
    const float* W_rbf1     = (const float*)d_in[6];
    const float* b_rbf1     = (const float*)d_in[7];
    const float* W_m0       = (const float*)d_in[8];
    const float* b_m0       = (const float*)d_in[9];
    const float* W_m1       = (const float*)d_in[10];
    const float* b_m1       = (const float*)d_in[11];
    const float* W_m2       = (const float*)d_in[12];
    const float* b_m2       = (const float*)d_in[13];
    const float* w_tp1      = (const float*)d_in[15];
    const float* L1o        = (const float*)d_in[18];
    const float* L_out      = (const float*)d_in[20];
    float* out = (float*)d_out;

    const int N = in_sizes[0] / 3;       // 200000
    const int G = out_size / 255;        // 8192
    const int ntiles = (N + 63) / 64;    // 3125

    char* ws = (char*)d_ws;
    float*    bc    = (float*)(ws + 0);           // 256 B
    float*    Lcomb = (float*)(ws + 256);         // 21760 -> 22016, pad 22528
    int*      seg   = (int*)(ws + 22528);         // 32772 -> 55300, pad 55552
    ushort_t* wb    = (ushort_t*)(ws + 55552);    // 81920 B -> 137472
    float*    tblc  = (float*)(ws + 137472);      // 25600 -> 163072
    float*    g1    = (float*)(ws + 163072);      // G*192*4 = 6291456 B

    (void)hipMemsetAsync(g1, 0, (size_t)G * 192 * sizeof(float), stream);

    const int segBlocks = (N + 255) / 256;
    prep_kernel<<<127 + segBlocks, 256, 0, stream>>>(
        W_rbf0, W_rbf1, W_m0, W_m1, W_m2, b_m0, b_m2, w_tp1, L1o, L_out,
        node_table, batch, wb, tblc, bc, Lcomb, seg, N, G);

    node_mfma_kernel<<<(ntiles + 3) / 4, 256, 0, stream>>>(
        pos, z, batch, wb, tblc, b_rbf0, b_rbf1, b_m1, bc, g1, N, ntiles);

    graph_final<<<(G + 3) / 4, 256, 0, stream>>>(g1, seg, Lcomb, out, G);
}

// Round 13
// 90.683 us; speedup vs baseline: 1.2573x; 1.0682x over previous
//
#include <hip/hip_runtime.h>
#include <hip/hip_bf16.h>

// Only the l=1 path reaches the output (g0/g2/c0/c2/w_tp0/w_tp2/L0/L2e are dead).
// t[i] = MLP(node i) @ (W_m2@w_tp1) + b_m2@w_tp1 ; enc = agg(segsum(t x sqrt3*pos)) @ (L1o@L_out)/64
// r13: DISAMBIGUATION ROUND. 128-node waves (half the wave count, 2x work/wave),
// acc[4][8], r7-proven in-place LDS + 0x7F fences, pos/batch stored in the row pad
// (reduction uses broadcast ds_read instead of dependent shfl chains).

typedef __attribute__((ext_vector_type(8))) short bf16x8;
typedef __attribute__((ext_vector_type(4))) float f32x4;
typedef unsigned short ushort_t;

#define SBW 72   // LDS act-row stride in ushorts: 64 act cols + 8 pad (pad holds pos.xyz+batch)

__device__ __forceinline__ unsigned rnebits(float x) {   // RNE, bf16 in top 16 bits (prep only)
    unsigned u = __float_as_uint(x);
    return u + 0x7fffu + ((u >> 16) & 1u);
}
__device__ __forceinline__ ushort_t f2bf(float x) { return (ushort_t)(rnebits(x) >> 16); }
__device__ __forceinline__ float bf2f(ushort_t h) { return __uint_as_float(((unsigned)h) << 16); }
__device__ __forceinline__ unsigned pk2(float lo, float hi) {   // HW v_cvt_pk_bf16_f32 (RNE)
    __hip_bfloat162 h2 = __float22bfloat162_rn(make_float2(lo, hi));
    unsigned r;
    __builtin_memcpy(&r, &h2, 4);
    return r;
}
__device__ __forceinline__ void ds_order_fence() {   // compile-time: DS ops may not cross
    __builtin_amdgcn_sched_barrier(0x7F);
}

// batched gelu pair: gelu(x) = x - x*rcp(exp2(y)+1), y = x*(C + Ca*x^2) clamped to 60
__device__ __forceinline__ void gelu2(float& a, float& b) {
    float ya = fminf(a * fmaf(0.10294324f, a * a, 2.3022082f), 60.0f);
    float yb = fminf(b * fmaf(0.10294324f, b * b, 2.3022082f), 60.0f);
    float sa = __builtin_amdgcn_exp2f(ya) + 1.0f;
    float sb = __builtin_amdgcn_exp2f(yb) + 1.0f;
    float R  = __builtin_amdgcn_rcpf(sa * sb);
    a = fmaf(-a, R * sb, a);
    b = fmaf(-b, R * sa, b);
}

// ---------------- prep (unchanged, passed since r7) ----------------
// wb ushort layout: layer L hi at L*8192, lo at L*8192+4096, all [64 feat][64 k] row-major.
//  L0=W_rbf0 zero-padded | L1=W_rbf1 | L2=W_m0[0:64] | L3=W_m1 | L4=Wc=W_m2@w_tp1
__global__ __launch_bounds__(256)
void prep_kernel(const float* __restrict__ W_rbf0, const float* __restrict__ W_rbf1,
                 const float* __restrict__ W_m0, const float* __restrict__ W_m1,
                 const float* __restrict__ W_m2, const float* __restrict__ b_m0,
                 const float* __restrict__ b_m2, const float* __restrict__ w_tp1,
                 const float* __restrict__ L1o, const float* __restrict__ L_out,
                 const float* __restrict__ node_table, const int* __restrict__ batch,
                 ushort_t* __restrict__ wb, float* __restrict__ tblc,
                 float* __restrict__ bc, float* __restrict__ Lcomb,
                 int* __restrict__ seg, int N, int G)
{
    if (blockIdx.x >= 127) {   // ---- seg part ----
        int i = (blockIdx.x - 127) * 256 + threadIdx.x;
        if (i >= N) return;
        int bi = batch[i];
        int bprev = (i == 0) ? -1 : batch[i - 1];
        for (int g = bprev + 1; g <= bi; ++g) seg[g] = i;
        if (i == N - 1) for (int g = bi + 1; g <= G; ++g) seg[g] = N;
        return;
    }
    int idx = blockIdx.x * 256 + threadIdx.x;   // fold part, 32384 items
    float w;
    ushort_t *dh, *dl;
    if (idx < 4096) {                    // L0: W_rbf0 zero-padded [f][64]
        int f = idx >> 6, k = idx & 63;
        w = (k < 32) ? W_rbf0[k * 64 + f] : 0.0f;
        dh = wb + idx; dl = wb + 4096 + idx;
    } else if (idx < 8192) {             // L1: W_rbf1 [f][64]
        int j = idx - 4096, f = j >> 6, k = j & 63;
        w = W_rbf1[k * 64 + f]; dh = wb + 8192 + j; dl = wb + 12288 + j;
    } else if (idx < 12288) {            // L2: W_m0 rows 0..63 [f][64]
        int j = idx - 8192, f = j >> 6, k = j & 63;
        w = W_m0[k * 64 + f]; dh = wb + 16384 + j; dl = wb + 20480 + j;
    } else if (idx < 16384) {            // L3: W_m1 [f][64]
        int j = idx - 12288, f = j >> 6, k = j & 63;
        w = W_m1[k * 64 + f]; dh = wb + 24576 + j; dl = wb + 28672 + j;
    } else if (idx < 20480) {            // L4: Wc[f][k] = sum_j W_m2[k][j]*w_tp1[j][f]
        int j = idx - 16384, f = j >> 6, k = j & 63;
        float s = 0.f;
        for (int jj = 0; jj < 64; ++jj) s = fmaf(W_m2[k * 64 + jj], w_tp1[jj * 64 + f], s);
        w = s; dh = wb + 32768 + j; dl = wb + 36864 + j;
    } else if (idx < 26880) {            // tblc[zz][f] = b_m0[f] + table[zz]@W_m0[64:96]  (f32)
        int j = idx - 20480, zz = j >> 6, f = j & 63;
        float s = b_m0[f];
        for (int k = 0; k < 32; ++k) s = fmaf(node_table[zz * 32 + k], W_m0[(64 + k) * 64 + f], s);
        tblc[j] = s;
        return;
    } else if (idx < 26944) {            // bc
        int b = idx - 26880;
        float s = 0.f;
        for (int k = 0; k < 64; ++k) s = fmaf(b_m2[k], w_tp1[k * 64 + b], s);
        bc[b] = s;
        return;
    } else if (idx < 32384) {            // Lcomb = (L1o@L_out)/64
        int j = idx - 26944, u = j / 85, v = j - 85 * u;
        float s = 0.f;
        for (int k = 0; k < 64; ++k) s = fmaf(L1o[u * 64 + k], L_out[k * 85 + v], s);
        Lcomb[j] = 0.015625f * s;
        return;
    } else return;
    ushort_t h = f2bf(w);
    *dh = h;
    *dl = f2bf(w - bf2f(h));
}

// ---------------- node MLP (128-node waves) + fused segment reduction ----------------
__global__ __launch_bounds__(128, 2)
void node_mfma_kernel(const float* __restrict__ pos, const int* __restrict__ z,
                      const int* __restrict__ batch,
                      const ushort_t* __restrict__ wb, const float* __restrict__ tblc,
                      const float* __restrict__ b_rbf0, const float* __restrict__ b_rbf1,
                      const float* __restrict__ b_m1, const float* __restrict__ bc,
                      float* __restrict__ g1, int N, int ntiles)
{
    __shared__ ushort_t bufs[2 * 128 * SBW];   // 36864 B -> 4 blocks/CU (8 waves/CU)
    const int wid = threadIdx.x >> 6;
    const int lane = threadIdx.x & 63;
    const int tile = blockIdx.x * 2 + wid;
    if (tile >= ntiles) return;               // no block-wide syncs anywhere
    ushort_t* buf = bufs + wid * (128 * SBW);

    const int lrow = lane >> 4, lcol = lane & 15;
    const int nodebase = tile * 128;
    const int nend = (N - nodebase) < 128 ? (N - nodebase) : 128;

    // ---- stage: each lane owns 2 rows (lane, lane+64): rbf cols 0..31, zeros 32..63,
    //      pos.xyz+batch in the 16B pad (cols 64..71) ----
    #pragma unroll
    for (int half = 0; half < 2; ++half) {
        const int nd = half * 64 + lane;
        int gn = nodebase + nd;
        if (gn > N - 1) gn = N - 1;
        float px = pos[3 * gn], py = pos[3 * gn + 1], pz = pos[3 * gn + 2];
        int   bb_ = batch[gn];
        float dist = sqrtf(px * px + py * py + pz * pz);
        unsigned rb[16];
        #pragma unroll
        for (int j = 0; j < 16; ++j) {
            float d0 = dist - (float)(2 * j)     * (1.0f / 31.0f);
            float d1 = dist - (float)(2 * j + 1) * (1.0f / 31.0f);
            rb[j] = pk2(__builtin_amdgcn_exp2f(-693.2149671554846f * d0 * d0),
                        __builtin_amdgcn_exp2f(-693.2149671554846f * d1 * d1));
        }
        uint4* dst = (uint4*)&buf[nd * SBW];
        dst[0] = make_uint4(rb[0], rb[1], rb[2], rb[3]);
        dst[1] = make_uint4(rb[4], rb[5], rb[6], rb[7]);
        dst[2] = make_uint4(rb[8], rb[9], rb[10], rb[11]);
        dst[3] = make_uint4(rb[12], rb[13], rb[14], rb[15]);
        uint4 zz4 = make_uint4(0, 0, 0, 0);
        dst[4] = zz4; dst[5] = zz4; dst[6] = zz4; dst[7] = zz4;
        dst[8] = make_uint4(__float_as_uint(px), __float_as_uint(py),
                            __float_as_uint(pz), (unsigned)bb_);
    }
    // z gather for layer-2 acc-init (node = n*16+lcol)
    int zn[8];
    #pragma unroll
    for (int n = 0; n < 8; ++n) {
        int nn = nodebase + n * 16 + lcol;
        if (nn > N - 1) nn = N - 1;
        zn[n] = z[nn];
    }
    ds_order_fence();

    #pragma unroll 1
    for (int L = 0; L < 5; ++L) {
        const ushort_t* whb = wb + L * 8192;
        f32x4 acc[4][8];
        if (L == 2) {   // per-node acc-init from tblc (f32-exact table contribution)
            #pragma unroll
            for (int n = 0; n < 8; ++n) {
                const float* tp = tblc + zn[n] * 64 + lrow * 4;
                #pragma unroll
                for (int m = 0; m < 4; ++m) {
                    float4 bv = *(const float4*)(tp + m * 16);
                    acc[m][n][0] = bv.x; acc[m][n][1] = bv.y;
                    acc[m][n][2] = bv.z; acc[m][n][3] = bv.w;
                }
            }
        } else {
            const float* bp = (L == 0) ? b_rbf0 : (L == 1) ? b_rbf1 : (L == 3) ? b_m1 : bc;
            #pragma unroll
            for (int m = 0; m < 4; ++m) {
                float4 bv = *(const float4*)(bp + m * 16 + lrow * 4);
                #pragma unroll
                for (int n = 0; n < 8; ++n) {
                    acc[m][n][0] = bv.x; acc[m][n][1] = bv.y;
                    acc[m][n][2] = bv.z; acc[m][n][3] = bv.w;
                }
            }
        }
        #pragma unroll
        for (int kt = 0; kt < 2; ++kt) {
            const int kof = kt * 32 + lrow * 8;
            bf16x8 bb[8], ah[4], al[4];
            #pragma unroll
            for (int n = 0; n < 8; ++n)
                bb[n] = *(const bf16x8*)&buf[(n * 16 + lcol) * SBW + kof];
            #pragma unroll
            for (int m = 0; m < 4; ++m) {
                ah[m] = *(const bf16x8*)(whb + (m * 16 + lcol) * 64 + kof);
                al[m] = *(const bf16x8*)(whb + 4096 + (m * 16 + lcol) * 64 + kof);
            }
            #pragma unroll
            for (int m = 0; m < 4; ++m)
                #pragma unroll
                for (int n = 0; n < 8; ++n)
                    acc[m][n] = __builtin_amdgcn_mfma_f32_16x16x32_bf16(ah[m], bb[n], acc[m][n], 0, 0, 0);
            #pragma unroll
            for (int m = 0; m < 4; ++m)
                #pragma unroll
                for (int n = 0; n < 8; ++n)
                    acc[m][n] = __builtin_amdgcn_mfma_f32_16x16x32_bf16(al[m], bb[n], acc[m][n], 0, 0, 0);
        }
        ds_order_fence();   // all reads of buf done before in-place writes
        const bool act = (L == 0) | (L == 2) | (L == 3);
        #pragma unroll
        for (int m = 0; m < 4; ++m) {
            const int f0 = m * 16 + lrow * 4;
            #pragma unroll
            for (int n = 0; n < 8; ++n) {
                f32x4 v = acc[m][n];
                float v0 = v[0], v1 = v[1], v2 = v[2], v3 = v[3];
                if (act) { gelu2(v0, v1); gelu2(v2, v3); }
                uint2 pk;
                pk.x = pk2(v0, v1);
                pk.y = pk2(v2, v3);
                *(uint2*)&buf[(n * 16 + lcol) * SBW + f0] = pk;
            }
        }
        ds_order_fence();   // writes done before next layer's reads
    }

    // ---- fused segment reduction: lane = feature, iterate this wave's nodes ----
    {
        float a0 = 0.f, a1 = 0.f, a2 = 0.f;
        int curg = -1;
        for (int nd = 0; nd < nend; ++nd) {
            uint4 pb = *(const uint4*)&buf[nd * SBW + 64];   // broadcast read: pos+batch
            int bg = (int)pb.w;
            if (bg != curg) {
                if (curg >= 0) {
                    atomicAdd(&g1[curg * 192 + lane],       a0);
                    atomicAdd(&g1[curg * 192 + 64 + lane],  a1);
                    atomicAdd(&g1[curg * 192 + 128 + lane], a2);
                    a0 = a1 = a2 = 0.f;
                }
                curg = bg;
            }
            float t = bf2f(buf[nd * SBW + lane]);
            a0 = fmaf(t, __uint_as_float(pb.x), a0);
            a1 = fmaf(t, __uint_as_float(pb.y), a1);
            a2 = fmaf(t, __uint_as_float(pb.z), a2);
        }
        if (curg >= 0) {
            atomicAdd(&g1[curg * 192 + lane],       a0);
            atomicAdd(&g1[curg * 192 + 64 + lane],  a1);
            atomicAdd(&g1[curg * 192 + 128 + lane], a2);
        }
    }
}

// ---------------- final: scale + Lcomb matmul (unchanged, passed) ----------------
__global__ __launch_bounds__(256)
void graph_final(const float* __restrict__ g1, const int* __restrict__ seg,
                 const float* __restrict__ Lcomb, float* __restrict__ out, int G) {
    __shared__ float g1s[4][64][3];
    const int lane = threadIdx.x & 63;
    const int wid = threadIdx.x >> 6;
    const int g = blockIdx.x * 4 + wid;
    const bool active = g < G;

    if (active) {
        int c = seg[g + 1] - seg[g];
        float cnt = (float)(c > 0 ? c : 1);
        float sc = 1.7320508075688772f * 0.125f * (1.0f + 1.0f / cnt);
        g1s[wid][lane][0] = g1[g * 192 + lane] * sc;
        g1s[wid][lane][1] = g1[g * 192 + 64 + lane] * sc;
        g1s[wid][lane][2] = g1[g * 192 + 128 + lane] * sc;
    }
    __syncthreads();
    if (!active) return;

    float o0 = 0.f, o1 = 0.f, o2 = 0.f, p0 = 0.f, p1 = 0.f, p2 = 0.f;
    const int v2 = 64 + lane;
    for (int u = 0; u < 64; ++u) {
        float b0 = g1s[wid][u][0], b1 = g1s[wid][u][1], b2 = g1s[wid][u][2];
        float l0 = Lcomb[u * 85 + lane];
        o0 = fmaf(b0, l0, o0); o1 = fmaf(b1, l0, o1); o2 = fmaf(b2, l0, o2);
        if (lane < 21) {
            float l1 = Lcomb[u * 85 + v2];
            p0 = fmaf(b0, l1, p0); p1 = fmaf(b1, l1, p1); p2 = fmaf(b2, l1, p2);
        }
    }
    float* og = out + (size_t)g * 255;
    og[3 * lane + 0] = o0; og[3 * lane + 1] = o1; og[3 * lane + 2] = o2;
    if (lane < 21) {
        og[3 * v2 + 0] = p0; og[3 * v2 + 1] = p1; og[3 * v2 + 2] = p2;
    }
}

extern "C" void kernel_launch(void* const* d_in, const int* in_sizes, int n_in,
                              void* d_out, int out_size, void* d_ws, size_t ws_size,
                              hipStream_t stream) {
    const float* pos        = (const float*)d_in[0];
    const int*   z          = (const int*)d_in[1];
    const int*   batch      = (const int*)d_in[2];
    const float* node_table = (const float*)d_in[3];
    const float* W_rbf0     = (const float*)d_in[4];
    const float* b_rbf0     = (const float*)d_in[5];
    const float* W_rbf1     = (const float*)d_in[6];
    const float* b_rbf1     = (const float*)d_in[7];
    const float* W_m0       = (const float*)d_in[8];
    const float* b_m0       = (const float*)d_in[9];
    const float* W_m1       = (const float*)d_in[10];
    const float* b_m1       = (const float*)d_in[11];
    const float* W_m2       = (const float*)d_in[12];
    const float* b_m2       = (const float*)d_in[13];
    const float* w_tp1      = (const float*)d_in[15];
    const float* L1o        = (const float*)d_in[18];
    const float* L_out      = (const float*)d_in[20];
    float* out = (float*)d_out;

    const int N = in_sizes[0] / 3;       // 200000
    const int G = out_size / 255;        // 8192
    const int ntiles = (N + 127) / 128;  // 1563

    char* ws = (char*)d_ws;
    float*    bc    = (float*)(ws + 0);           // 256 B
    float*    Lcomb = (float*)(ws + 256);         // 21760 -> 22016, pad 22528
    int*      seg   = (int*)(ws + 22528);         // 32772 -> 55300, pad 55552
    ushort_t* wb    = (ushort_t*)(ws + 55552);    // 81920 B -> 137472
    float*    tblc  = (float*)(ws + 137472);      // 25600 -> 163072
    float*    g1    = (float*)(ws + 163072);      // G*192*4 = 6291456 B

    (void)hipMemsetAsync(g1, 0, (size_t)G * 192 * sizeof(float), stream);

    const int segBlocks = (N + 255) / 256;
    prep_kernel<<<127 + segBlocks, 256, 0, stream>>>(
        W_rbf0, W_rbf1, W_m0, W_m1, W_m2, b_m0, b_m2, w_tp1, L1o, L_out,
        node_table, batch, wb, tblc, bc, Lcomb, seg, N, G);

    node_mfma_kernel<<<(ntiles + 1) / 2, 128, 0, stream>>>(
        pos, z, batch, wb, tblc, b_rbf0, b_rbf1, b_m1, bc, g1, N, ntiles);

    graph_final<<<(G + 3) / 4, 256, 0, stream>>>(g1, seg, Lcomb, out, G);
}